// Round 10
// baseline (94.598 us; speedup 1.0000x reference)
//
#include <hip/hip_runtime.h>

// out[i,j] = (z[i,:] . w) * w[j] + bias[j], all f32.  S=65536, B=1024.
// R10 = R9 with amortization pushed one notch:
//   dot4:   4 rows/block  -> each w[i] load feeds 4 z-row FMAs
//   outer8: 8 rows/block  -> each w[i]/bias[i] load feeds 8 NT row-stores
// NT stores keep `out` from evicting z in L3; plain loads for z (NT loads
// regressed in R8 by killing z's cross-replay L3 residency).

#define SDIM 65536
#define S4   16384     // float4 per row
#define BLK  512

typedef float floatx4 __attribute__((ext_vector_type(4)));

__device__ __forceinline__ float dot4(floatx4 a, floatx4 b) {
    return a.x * b.x + a.y * b.y + a.z * b.z + a.w * b.w;
}

// ---------------- kernel A: scal[r] = z[r,:] . w, 4 rows per block ----------
__global__ __launch_bounds__(BLK) void dot4_kernel(
    const float* __restrict__ z,
    const float* __restrict__ w,
    float* __restrict__ scal)
{
    const int r0 = blockIdx.x * 4;
    const floatx4* __restrict__ z0 =
        reinterpret_cast<const floatx4*>(z + (size_t)r0 * SDIM);
    const floatx4* __restrict__ z1 =
        reinterpret_cast<const floatx4*>(z + (size_t)(r0 + 1) * SDIM);
    const floatx4* __restrict__ z2 =
        reinterpret_cast<const floatx4*>(z + (size_t)(r0 + 2) * SDIM);
    const floatx4* __restrict__ z3 =
        reinterpret_cast<const floatx4*>(z + (size_t)(r0 + 3) * SDIM);
    const floatx4* __restrict__ w4 = reinterpret_cast<const floatx4*>(w);

    // unroll 2: per iter 2 w loads + 8 z loads, 8 accumulator chains
    float a00 = 0.f, a01 = 0.f, a10 = 0.f, a11 = 0.f;
    float a20 = 0.f, a21 = 0.f, a30 = 0.f, a31 = 0.f;
    for (int i = threadIdx.x; i < S4; i += 2 * BLK) {
        floatx4 y0 = w4[i];
        floatx4 y1 = w4[i + BLK];
        floatx4 p0 = z0[i];
        floatx4 p1 = z0[i + BLK];
        floatx4 q0 = z1[i];
        floatx4 q1 = z1[i + BLK];
        floatx4 u0 = z2[i];
        floatx4 u1 = z2[i + BLK];
        floatx4 v0 = z3[i];
        floatx4 v1 = z3[i + BLK];
        a00 += dot4(p0, y0); a01 += dot4(p1, y1);
        a10 += dot4(q0, y0); a11 += dot4(q1, y1);
        a20 += dot4(u0, y0); a21 += dot4(u1, y1);
        a30 += dot4(v0, y0); a31 += dot4(v1, y1);
    }
    float acc0 = a00 + a01;
    float acc1 = a10 + a11;
    float acc2 = a20 + a21;
    float acc3 = a30 + a31;

    #pragma unroll
    for (int off = 32; off > 0; off >>= 1) {
        acc0 += __shfl_down(acc0, off, 64);
        acc1 += __shfl_down(acc1, off, 64);
        acc2 += __shfl_down(acc2, off, 64);
        acc3 += __shfl_down(acc3, off, 64);
    }

    __shared__ float smem[BLK / 64][4];
    const int lane = threadIdx.x & 63;
    const int wid  = threadIdx.x >> 6;
    if (lane == 0) {
        smem[wid][0] = acc0; smem[wid][1] = acc1;
        smem[wid][2] = acc2; smem[wid][3] = acc3;
    }
    __syncthreads();
    if (threadIdx.x < 4) {
        const int r = threadIdx.x;
        float t = 0.f;
        #pragma unroll
        for (int i = 0; i < BLK / 64; ++i) t += smem[i][r];
        scal[r0 + r] = t;
    }
}

// ------------- kernel B: out[r,:] = scal[r]*w + bias, 8 rows per block ------
#define OBLK   256
#define ORROWS 8
#define NCHUNK 8
#define CHUNK4 (S4 / NCHUNK)   // 2048 float4

__global__ __launch_bounds__(OBLK) void outer8_kernel(
    const float* __restrict__ scal,
    const float* __restrict__ w,
    const float* __restrict__ bias,
    float* __restrict__ out)
{
    const int group = blockIdx.x >> 3;        // row group of 8
    const int chunk = blockIdx.x & (NCHUNK - 1);
    const int r0    = group * ORROWS;
    const int base  = chunk * CHUNK4;

    float s[ORROWS];
    #pragma unroll
    for (int r = 0; r < ORROWS; ++r) s[r] = scal[r0 + r];

    const floatx4* __restrict__ w4 = reinterpret_cast<const floatx4*>(w) + base;
    const floatx4* __restrict__ b4 = reinterpret_cast<const floatx4*>(bias) + base;

    // 2048 f4 / 256 thr = 8 iters; unroll 2 -> per iter 4 loads, 16 NT stores
    for (int i = threadIdx.x; i < CHUNK4; i += 2 * OBLK) {
        floatx4 y0 = w4[i];
        floatx4 y1 = w4[i + OBLK];
        floatx4 c0 = b4[i];
        floatx4 c1 = b4[i + OBLK];

        #pragma unroll
        for (int r = 0; r < ORROWS; ++r) {
            floatx4* orow =
                reinterpret_cast<floatx4*>(out + (size_t)(r0 + r) * SDIM) + base;
            floatx4 t;
            t.x = fmaf(s[r], y0.x, c0.x); t.y = fmaf(s[r], y0.y, c0.y);
            t.z = fmaf(s[r], y0.z, c0.z); t.w = fmaf(s[r], y0.w, c0.w);
            __builtin_nontemporal_store(t, &orow[i]);
            t.x = fmaf(s[r], y1.x, c1.x); t.y = fmaf(s[r], y1.y, c1.y);
            t.z = fmaf(s[r], y1.z, c1.z); t.w = fmaf(s[r], y1.w, c1.w);
            __builtin_nontemporal_store(t, &orow[i + OBLK]);
        }
    }
}

extern "C" void kernel_launch(void* const* d_in, const int* in_sizes, int n_in,
                              void* d_out, int out_size, void* d_ws, size_t ws_size,
                              hipStream_t stream)
{
    const float* z    = (const float*)d_in[0];
    const float* w    = (const float*)d_in[1];  // (1,S,1) flat == (S,)
    const float* bias = (const float*)d_in[2];
    float* out  = (float*)d_out;
    float* scal = (float*)d_ws;                 // B floats of scratch

    const int B = in_sizes[0] / SDIM;           // 1024

    dot4_kernel<<<B / 4, BLK, 0, stream>>>(z, w, scal);
    outer8_kernel<<<(B / ORROWS) * NCHUNK, OBLK, 0, stream>>>(scal, w, bias, out);
}